// Round 1
// 505.766 us; speedup vs baseline: 1.0191x; 1.0191x over previous
//
#include <hip/hip_runtime.h>
#include <hip/hip_fp16.h>
#include <math.h>

// ---------------------------------------------------------------------------
// SimSiam head loss, 12 heads, fp32 in, B=8 H=512 W=768 -> per head (8,3,512,256)
//
// R3 structure (dependency-chain restructure, single in-place fp16 buffer):
//   passA1: read fp32 x (302 MB) -> x 9-moments, write fp16(x) into ws (151 MB)
//   statsF(0):  bn1 analytic from x-moments -> folded (W1f, c1)
//   passA2: read fp16 x (L3-hot), a = relu(W1f x + c1), 9-moments(a),
//           OVERWRITE ws in place with fp16(a)      [=> bn2 analytic, passB gone]
//   statsF(12): bn2 analytic (y2 = W2 a + b2 is linear in a)
//   passC2: read fp16 a, a2 = relu(W2f a + c2), 9-moments(a2), in-place fp16(a2)
//   statsC2: bn3 + bn4 analytic from a2-moments
//   passD2: read fp16 a2 both latents, z = W3f a2 + c3,
//           p = w5*relu(w4s.z + b4c) + b5, cosine loss (rsqrt form)
// Hot working set = one 151 MB buffer rewritten in place -> stays L3-resident
// for A2/C2/D2. Fallback (<NEED ws): recompute from fp32 x each pass.
// ---------------------------------------------------------------------------

typedef unsigned short ushort_t;
typedef unsigned int   uint_t;

constexpr int   NH      = 12;
constexpr int   POS     = 131072;               // floats per channel per (b,head)
constexpr int   NB      = 8;
constexpr long long MLL = (long long)NB * POS;  // 1,048,576 positions per slice
constexpr int   CSPAN   = POS / 16;             // 8192 floats/channel per block
constexpr int   SBLK    = 128;                  // blocks per slice = 8 b * 16 x
constexpr int   NTOT    = NB * NH * 3 * POS;    // 37,748,736 elements per latent

constexpr size_t XH_BYTES   = (size_t)NTOT * 2;             // fp16 per latent
constexpr size_t P_CNT      = (size_t)24 * SBLK * 9;        // doubles per P array
constexpr size_t DBL_COUNT  = 3 * P_CNT + (size_t)12 * SBLK;
constexpr size_t NEED_BYTES = 2 * XH_BYTES + DBL_COUNT * 8 + (size_t)24 * 40 * 4;

// ---------------- block reduction: 256 threads -> thread 0 ----------------
template <int K>
__device__ inline void block_reduce_to0(double (&v)[K]) {
#pragma unroll
  for (int off = 32; off > 0; off >>= 1) {
#pragma unroll
    for (int k = 0; k < K; ++k) v[k] += __shfl_down(v[k], off, 64);
  }
  __shared__ double lds[4][K];
  const int lane = threadIdx.x & 63;
  const int wv   = threadIdx.x >> 6;
  if (lane == 0) {
#pragma unroll
    for (int k = 0; k < K; ++k) lds[wv][k] = v[k];
  }
  __syncthreads();
  if (threadIdx.x == 0) {
#pragma unroll
    for (int k = 0; k < K; ++k) v[k] = lds[0][k] + lds[1][k] + lds[2][k] + lds[3][k];
  }
}

// ---------------- fp16 helpers ----------------
__device__ inline uint_t pack2h(float lo, float hi) {     // RNE
  return (uint_t)__half_as_ushort(__float2half(lo)) |
         ((uint_t)__half_as_ushort(__float2half(hi)) << 16);
}
__device__ inline float h_lo(uint_t w) {
  return __half2float(__ushort_as_half((unsigned short)(w & 0xFFFFu)));
}
__device__ inline float h_hi(uint_t w) {
  return __half2float(__ushort_as_half((unsigned short)(w >> 16)));
}

// load 8 consecutive positions for all 3 channels
template <bool H16>
__device__ inline void load3x8(const float* __restrict__ X,
                               const ushort_t* __restrict__ XH,
                               size_t e, float (&f)[3][8]) {
#pragma unroll
  for (int c = 0; c < 3; ++c) {
    const size_t a = e + (size_t)c * POS;
    if constexpr (H16) {
      const uint4 v = *(const uint4*)(XH + a);
      f[c][0] = h_lo(v.x); f[c][1] = h_hi(v.x);
      f[c][2] = h_lo(v.y); f[c][3] = h_hi(v.y);
      f[c][4] = h_lo(v.z); f[c][5] = h_hi(v.z);
      f[c][6] = h_lo(v.w); f[c][7] = h_hi(v.w);
    } else {
      const float4 u0 = *(const float4*)(X + a);
      const float4 u1 = *(const float4*)(X + a + 4);
      f[c][0] = u0.x; f[c][1] = u0.y; f[c][2] = u0.z; f[c][3] = u0.w;
      f[c][4] = u1.x; f[c][5] = u1.y; f[c][6] = u1.z; f[c][7] = u1.w;
    }
  }
}

__device__ inline void store8h(ushort_t* __restrict__ XH, size_t e,
                               const float (&g)[8]) {
  uint4 h;
  h.x = pack2h(g[0], g[1]);
  h.y = pack2h(g[2], g[3]);
  h.z = pack2h(g[4], g[5]);
  h.w = pack2h(g[6], g[7]);
  *(uint4*)(XH + e) = h;
}

// ---------------- pass A1: raw moments of x (+ fp16 store) ----------------
template <bool STORE>
__global__ __launch_bounds__(256) void passA1_kernel(
    const float* __restrict__ x1, const float* __restrict__ x2,
    ushort_t* __restrict__ xh1, ushort_t* __restrict__ xh2,
    double* __restrict__ P0) {
  const int u = blockIdx.y;        // 0..191
  const int s = u % 24;
  const int b = u / 24;
  const int n = s >> 1;
  const float* __restrict__ X = (s & 1) ? x2 : x1;
  ushort_t* __restrict__ XH = (s & 1) ? xh2 : xh1;
  const size_t off0 = (size_t)((b * NH + n) * 3) * POS + (size_t)blockIdx.x * CSPAN;

  float acc[9] = {0.f, 0.f, 0.f, 0.f, 0.f, 0.f, 0.f, 0.f, 0.f};
#pragma unroll 2
  for (int i = 0; i < 4; ++i) {
    const size_t e = off0 + i * 2048 + threadIdx.x * 8;
    float f[3][8];
    load3x8<false>(X, nullptr, e, f);
    if constexpr (STORE) {
#pragma unroll
      for (int c = 0; c < 3; ++c) store8h(XH, e + (size_t)c * POS, f[c]);
    }
#pragma unroll
    for (int j = 0; j < 8; ++j) {
      const float X0 = f[0][j], X1 = f[1][j], X2 = f[2][j];
      acc[0] += X0;      acc[1] += X1;      acc[2] += X2;
      acc[3] += X0 * X0; acc[4] += X1 * X1; acc[5] += X2 * X2;
      acc[6] += X0 * X1; acc[7] += X0 * X2; acc[8] += X1 * X2;
    }
  }

  double v9[9];
#pragma unroll
  for (int k = 0; k < 9; ++k) v9[k] = (double)acc[k];
  block_reduce_to0<9>(v9);
  if (threadIdx.x == 0) {
    double* dst = P0 + ((size_t)s * SBLK + b * 16 + blockIdx.x) * 9;
#pragma unroll
    for (int k = 0; k < 9; ++k) dst[k] = v9[k];
  }
}

// ---------------- raw moments -> mean/cov ----------------
__device__ inline void moments_to_mc(const double (&v)[9], double (&m)[3],
                                     double (&C)[3][3]) {
  const double M = (double)MLL;
  m[0] = v[0] / M; m[1] = v[1] / M; m[2] = v[2] / M;
  C[0][0] = v[3] / M - m[0] * m[0];
  C[1][1] = v[4] / M - m[1] * m[1];
  C[2][2] = v[5] / M - m[2] * m[2];
  C[0][1] = C[1][0] = v[6] / M - m[0] * m[1];
  C[0][2] = C[2][0] = v[7] / M - m[0] * m[2];
  C[1][2] = C[2][1] = v[8] / M - m[1] * m[2];
}

// ---- analytic BN of y = Wk*t + bk from raw moments of t, folded output ----
// derived[s*40+outoff + o*3+c] = s_o*Wk[o][c];  derived[s*40+outoff+9+o] = s_o*bk[o]+t_o
__global__ __launch_bounds__(256) void stats_fold_kernel(
    const double* __restrict__ P, const float* __restrict__ Wk,
    const float* __restrict__ bk, const float* __restrict__ gk,
    const float* __restrict__ bek, float* __restrict__ derived, int outoff) {
  const int s = blockIdx.x;
  const int t = threadIdx.x;
  const int n = s >> 1;
  double v[9] = {0, 0, 0, 0, 0, 0, 0, 0, 0};
  if (t < SBLK) {
    const double* p = P + ((size_t)s * SBLK + t) * 9;
#pragma unroll
    for (int k = 0; k < 9; ++k) v[k] = p[k];
  }
  block_reduce_to0<9>(v);
  if (t == 0) {
    double m[3], C[3][3];
    moments_to_mc(v, m, C);
    for (int o = 0; o < 3; ++o) {
      const double w0 = Wk[n * 9 + o * 3 + 0];
      const double w1 = Wk[n * 9 + o * 3 + 1];
      const double w2 = Wk[n * 9 + o * 3 + 2];
      const double my = w0 * m[0] + w1 * m[1] + w2 * m[2] + (double)bk[n * 3 + o];
      const double vy = w0 * w0 * C[0][0] + w1 * w1 * C[1][1] + w2 * w2 * C[2][2] +
                        2.0 * (w0 * w1 * C[0][1] + w0 * w2 * C[0][2] + w1 * w2 * C[1][2]);
      const double sc = (double)gk[n * 3 + o] / sqrt(vy + 1e-5);
      const double tt = (double)bek[n * 3 + o] - my * sc;
      derived[s * 40 + outoff + o * 3 + 0] = (float)(sc * w0);
      derived[s * 40 + outoff + o * 3 + 1] = (float)(sc * w1);
      derived[s * 40 + outoff + o * 3 + 2] = (float)(sc * w2);
      derived[s * 40 + outoff + 9 + o]     = (float)(sc * (double)bk[n * 3 + o] + tt);
    }
  }
}

// ---------------- pass A2: a = relu(bn1), moments(a), in-place store ----------------
template <bool H16>
__global__ __launch_bounds__(256) void passA2_kernel(
    const float* __restrict__ x1, const float* __restrict__ x2,
    ushort_t* __restrict__ xh1, ushort_t* __restrict__ xh2,
    const float* __restrict__ derived, double* __restrict__ P1) {
  const int u = blockIdx.y;
  const int s = u % 24;
  const int b = u / 24;
  const int n = s >> 1;
  const float* __restrict__ X = (s & 1) ? x2 : x1;
  ushort_t* __restrict__ XH = (s & 1) ? xh2 : xh1;
  const size_t off0 = (size_t)((b * NH + n) * 3) * POS + (size_t)blockIdx.x * CSPAN;

  const float* D = derived + s * 40;
  float w1f[3][3], c1v[3];
#pragma unroll
  for (int o = 0; o < 3; ++o) {
#pragma unroll
    for (int c = 0; c < 3; ++c) w1f[o][c] = D[o * 3 + c];
    c1v[o] = D[9 + o];
  }

  float acc[9] = {0.f, 0.f, 0.f, 0.f, 0.f, 0.f, 0.f, 0.f, 0.f};
#pragma unroll 2
  for (int i = 0; i < 4; ++i) {
    const size_t e = off0 + i * 2048 + threadIdx.x * 8;
    float f[3][8];
    load3x8<H16>(X, XH, e, f);
    float A[3][8];
#pragma unroll
    for (int j = 0; j < 8; ++j) {
      const float X0 = f[0][j], X1 = f[1][j], X2 = f[2][j];
#pragma unroll
      for (int o = 0; o < 3; ++o)
        A[o][j] = fmaxf(0.f, fmaf(w1f[o][0], X0,
                         fmaf(w1f[o][1], X1, fmaf(w1f[o][2], X2, c1v[o]))));
      const float A0 = A[0][j], A1 = A[1][j], A2v = A[2][j];
      acc[0] += A0;       acc[1] += A1;       acc[2] += A2v;
      acc[3] += A0 * A0;  acc[4] += A1 * A1;  acc[5] += A2v * A2v;
      acc[6] += A0 * A1;  acc[7] += A0 * A2v; acc[8] += A1 * A2v;
    }
    if constexpr (H16) {
#pragma unroll
      for (int c = 0; c < 3; ++c) store8h(XH, e + (size_t)c * POS, A[c]);
    }
  }

  double v9[9];
#pragma unroll
  for (int k = 0; k < 9; ++k) v9[k] = (double)acc[k];
  block_reduce_to0<9>(v9);
  if (threadIdx.x == 0) {
    double* dst = P1 + ((size_t)s * SBLK + b * 16 + blockIdx.x) * 9;
#pragma unroll
    for (int k = 0; k < 9; ++k) dst[k] = v9[k];
  }
}

// ---------------- pass C2: a2 = relu(bn2), moments(a2), in-place store ----------------
template <bool H16>
__global__ __launch_bounds__(256) void passC2_kernel(
    const float* __restrict__ x1, const float* __restrict__ x2,
    ushort_t* __restrict__ xh1, ushort_t* __restrict__ xh2,
    const float* __restrict__ derived, double* __restrict__ P2) {
  const int u = blockIdx.y;
  const int s = u % 24;
  const int b = u / 24;
  const int n = s >> 1;
  const float* __restrict__ X = (s & 1) ? x2 : x1;
  ushort_t* __restrict__ XH = (s & 1) ? xh2 : xh1;
  const size_t off0 = (size_t)((b * NH + n) * 3) * POS + (size_t)blockIdx.x * CSPAN;

  const float* D = derived + s * 40;
  float w1f[3][3], c1v[3];
  if constexpr (!H16) {
#pragma unroll
    for (int o = 0; o < 3; ++o) {
#pragma unroll
      for (int c = 0; c < 3; ++c) w1f[o][c] = D[o * 3 + c];
      c1v[o] = D[9 + o];
    }
  }
  float w2f[3][3], c2v[3];
#pragma unroll
  for (int o = 0; o < 3; ++o) {
#pragma unroll
    for (int c = 0; c < 3; ++c) w2f[o][c] = D[12 + o * 3 + c];
    c2v[o] = D[21 + o];
  }

  float acc[9] = {0.f, 0.f, 0.f, 0.f, 0.f, 0.f, 0.f, 0.f, 0.f};
#pragma unroll 2
  for (int i = 0; i < 4; ++i) {
    const size_t e = off0 + i * 2048 + threadIdx.x * 8;
    float f[3][8];
    load3x8<H16>(X, XH, e, f);
    float A[3][8];
#pragma unroll
    for (int j = 0; j < 8; ++j) {
      float a0, a1, a2;
      if constexpr (H16) {
        a0 = f[0][j]; a1 = f[1][j]; a2 = f[2][j];
      } else {
        const float X0 = f[0][j], X1 = f[1][j], X2 = f[2][j];
        a0 = fmaxf(0.f, fmaf(w1f[0][0], X0, fmaf(w1f[0][1], X1, fmaf(w1f[0][2], X2, c1v[0]))));
        a1 = fmaxf(0.f, fmaf(w1f[1][0], X0, fmaf(w1f[1][1], X1, fmaf(w1f[1][2], X2, c1v[1]))));
        a2 = fmaxf(0.f, fmaf(w1f[2][0], X0, fmaf(w1f[2][1], X1, fmaf(w1f[2][2], X2, c1v[2]))));
      }
#pragma unroll
      for (int o = 0; o < 3; ++o)
        A[o][j] = fmaxf(0.f, fmaf(w2f[o][0], a0,
                         fmaf(w2f[o][1], a1, fmaf(w2f[o][2], a2, c2v[o]))));
      const float A0 = A[0][j], A1 = A[1][j], A2v = A[2][j];
      acc[0] += A0;       acc[1] += A1;       acc[2] += A2v;
      acc[3] += A0 * A0;  acc[4] += A1 * A1;  acc[5] += A2v * A2v;
      acc[6] += A0 * A1;  acc[7] += A0 * A2v; acc[8] += A1 * A2v;
    }
    if constexpr (H16) {
#pragma unroll
      for (int c = 0; c < 3; ++c) store8h(XH, e + (size_t)c * POS, A[c]);
    }
  }

  double v9[9];
#pragma unroll
  for (int k = 0; k < 9; ++k) v9[k] = (double)acc[k];
  block_reduce_to0<9>(v9);
  if (threadIdx.x == 0) {
    double* dst = P2 + ((size_t)s * SBLK + b * 16 + blockIdx.x) * 9;
#pragma unroll
    for (int k = 0; k < 9; ++k) dst[k] = v9[k];
  }
}

// ---------------- bn3 + bn4 stats (analytic from a2-moments) ----------------
__global__ __launch_bounds__(256) void statsC2_kernel(
    const double* __restrict__ P2, const float* __restrict__ W3,
    const float* __restrict__ b3, const float* __restrict__ g3,
    const float* __restrict__ be3, const float* __restrict__ W4,
    const float* __restrict__ b4, const float* __restrict__ g4,
    const float* __restrict__ be4, float* __restrict__ derived) {
  const int s = blockIdx.x;
  const int t = threadIdx.x;
  const int n = s >> 1;
  double v[9] = {0, 0, 0, 0, 0, 0, 0, 0, 0};
  if (t < SBLK) {
    const double* p = P2 + ((size_t)s * SBLK + t) * 9;
#pragma unroll
    for (int k = 0; k < 9; ++k) v[k] = p[k];
  }
  block_reduce_to0<9>(v);
  if (t == 0) {
    double m[3], C[3][3];
    moments_to_mc(v, m, C);
    double F3d[3][3], c3d[3];
    for (int o = 0; o < 3; ++o) {
      const double w0 = W3[n * 9 + o * 3 + 0];
      const double w1 = W3[n * 9 + o * 3 + 1];
      const double w2 = W3[n * 9 + o * 3 + 2];
      const double m3 = w0 * m[0] + w1 * m[1] + w2 * m[2] + (double)b3[n * 3 + o];
      const double vy = w0 * w0 * C[0][0] + w1 * w1 * C[1][1] + w2 * w2 * C[2][2] +
                        2.0 * (w0 * w1 * C[0][1] + w0 * w2 * C[0][2] + w1 * w2 * C[1][2]);
      const double s3 = (double)g3[n * 3 + o] / sqrt(vy + 1e-5);
      const double t3 = (double)be3[n * 3 + o] - m3 * s3;
      F3d[o][0] = s3 * w0; F3d[o][1] = s3 * w1; F3d[o][2] = s3 * w2;
      c3d[o] = s3 * (double)b3[n * 3 + o] + t3;
      derived[s * 40 + 24 + o * 3 + 0] = (float)F3d[o][0];
      derived[s * 40 + 24 + o * 3 + 1] = (float)F3d[o][1];
      derived[s * 40 + 24 + o * 3 + 2] = (float)F3d[o][2];
      derived[s * 40 + 33 + o]         = (float)c3d[o];
    }
    // predictor bn4: y4 = w4.z + b4 = q.a2 + d (linear in a2)
    double q[3] = {0.0, 0.0, 0.0};
    double d = (double)b4[n];
    for (int o = 0; o < 3; ++o) {
      const double w4o = W4[n * 3 + o];
      q[0] += w4o * F3d[o][0];
      q[1] += w4o * F3d[o][1];
      q[2] += w4o * F3d[o][2];
      d += w4o * c3d[o];
    }
    const double m4 = q[0] * m[0] + q[1] * m[1] + q[2] * m[2] + d;
    double v4 = 0.0;
    for (int i2 = 0; i2 < 3; ++i2)
      for (int j2 = 0; j2 < 3; ++j2) v4 += q[i2] * q[j2] * C[i2][j2];
    const double s4 = (double)g4[n] / sqrt(v4 + 1e-5);
    const double t4 = (double)be4[n] - m4 * s4;
    for (int o = 0; o < 3; ++o)
      derived[s * 40 + 36 + o] = (float)(s4 * (double)W4[n * 3 + o]);
    derived[s * 40 + 39] = (float)(s4 * (double)b4[n] + t4);
  }
}

// ---------------- tail chain: (a2 | x) -> z, p ----------------
template <bool H16>
__device__ inline void tail_chain(
    const float (&F1)[3][3], const float (&C1)[3],
    const float (&F2)[3][3], const float (&C2)[3],
    const float (&F3)[3][3], const float (&C3)[3],
    const float (&W4s)[3], float B4c,
    const float (&w5)[3], const float (&b5v)[3],
    float v0, float v1, float v2, float (&z)[3], float (&p)[3]) {
  float a0 = v0, a1 = v1, a2 = v2;
  if constexpr (!H16) {  // raw x: recompute layers 1-2
    const float t0 = fmaxf(0.f, fmaf(F1[0][0], v0, fmaf(F1[0][1], v1, fmaf(F1[0][2], v2, C1[0]))));
    const float t1 = fmaxf(0.f, fmaf(F1[1][0], v0, fmaf(F1[1][1], v1, fmaf(F1[1][2], v2, C1[1]))));
    const float t2 = fmaxf(0.f, fmaf(F1[2][0], v0, fmaf(F1[2][1], v1, fmaf(F1[2][2], v2, C1[2]))));
    a0 = fmaxf(0.f, fmaf(F2[0][0], t0, fmaf(F2[0][1], t1, fmaf(F2[0][2], t2, C2[0]))));
    a1 = fmaxf(0.f, fmaf(F2[1][0], t0, fmaf(F2[1][1], t1, fmaf(F2[1][2], t2, C2[1]))));
    a2 = fmaxf(0.f, fmaf(F2[2][0], t0, fmaf(F2[2][1], t1, fmaf(F2[2][2], t2, C2[2]))));
  }
#pragma unroll
  for (int o = 0; o < 3; ++o)
    z[o] = fmaf(F3[o][0], a0, fmaf(F3[o][1], a1, fmaf(F3[o][2], a2, C3[o])));
  const float y4 = fmaf(W4s[0], z[0], fmaf(W4s[1], z[1], fmaf(W4s[2], z[2], B4c)));
  const float h = fmaxf(0.f, y4);
#pragma unroll
  for (int o = 0; o < 3; ++o) p[o] = fmaf(w5[o], h, b5v[o]);
}

// ---------------- pass D2: cosine loss from a2 ----------------
template <bool H16>
__global__ __launch_bounds__(256) void passD2_kernel(
    const float* __restrict__ x1, const float* __restrict__ x2,
    const ushort_t* __restrict__ xh1, const ushort_t* __restrict__ xh2,
    const float* __restrict__ W5, const float* __restrict__ b5,
    const float* __restrict__ derived, double* __restrict__ PL) {
  const int u = blockIdx.y;        // 0..95
  const int n = u % 12;
  const int b = u / 12;
  const size_t off0 = (size_t)((b * NH + n) * 3) * POS + (size_t)blockIdx.x * CSPAN;

  float F1[2][3][3], C1[2][3], F2[2][3][3], C2[2][3];
  float F3[2][3][3], C3[2][3], W4s[2][3], B4c[2];
#pragma unroll
  for (int br = 0; br < 2; ++br) {
    const float* D = derived + (size_t)(2 * n + br) * 40;
    if constexpr (!H16) {
#pragma unroll
      for (int o = 0; o < 3; ++o) {
#pragma unroll
        for (int c = 0; c < 3; ++c) {
          F1[br][o][c] = D[o * 3 + c];
          F2[br][o][c] = D[12 + o * 3 + c];
        }
        C1[br][o] = D[9 + o];
        C2[br][o] = D[21 + o];
      }
    }
#pragma unroll
    for (int o = 0; o < 3; ++o) {
#pragma unroll
      for (int c = 0; c < 3; ++c) F3[br][o][c] = D[24 + o * 3 + c];
      C3[br][o]  = D[33 + o];
      W4s[br][o] = D[36 + o];
    }
    B4c[br] = D[39];
  }
  float w5[3], b5v[3];
#pragma unroll
  for (int o = 0; o < 3; ++o) {
    w5[o]  = W5[n * 3 + o];
    b5v[o] = b5[n * 3 + o];
  }

  float acc = 0.f;
  for (int i = 0; i < 4; ++i) {
    const size_t e = off0 + i * 2048 + threadIdx.x * 8;
    float fA[3][8], fB[3][8];
    load3x8<H16>(x1, xh1, e, fA);
    load3x8<H16>(x2, xh2, e, fB);
#pragma unroll
    for (int j = 0; j < 8; ++j) {
      float z1[3], p1[3], z2[3], p2[3];
      tail_chain<H16>(F1[0], C1[0], F2[0], C2[0], F3[0], C3[0], W4s[0], B4c[0],
                      w5, b5v, fA[0][j], fA[1][j], fA[2][j], z1, p1);
      tail_chain<H16>(F1[1], C1[1], F2[1], C2[1], F3[1], C3[1], W4s[1], B4c[1],
                      w5, b5v, fB[0][j], fB[1][j], fB[2][j], z2, p2);

      const float d12 = p1[0] * z2[0] + p1[1] * z2[1] + p1[2] * z2[2];
      const float pp1 = p1[0] * p1[0] + p1[1] * p1[1] + p1[2] * p1[2];
      const float zz2 = z2[0] * z2[0] + z2[1] * z2[1] + z2[2] * z2[2];
      acc += d12 * __builtin_amdgcn_rsqf(fmaxf(pp1, 1e-16f)) *
                   __builtin_amdgcn_rsqf(fmaxf(zz2, 1e-16f));

      const float d21 = p2[0] * z1[0] + p2[1] * z1[1] + p2[2] * z1[2];
      const float pp2 = p2[0] * p2[0] + p2[1] * p2[1] + p2[2] * p2[2];
      const float zz1 = z1[0] * z1[0] + z1[1] * z1[1] + z1[2] * z1[2];
      acc += d21 * __builtin_amdgcn_rsqf(fmaxf(pp2, 1e-16f)) *
                   __builtin_amdgcn_rsqf(fmaxf(zz1, 1e-16f));
    }
  }

  double v[1] = {(double)acc};
  block_reduce_to0<1>(v);
  if (threadIdx.x == 0) PL[(size_t)n * SBLK + b * 16 + blockIdx.x] = v[0];
}

// ---------------- finalize ----------------
__global__ __launch_bounds__(256) void finalize_kernel(
    const double* __restrict__ PL, float* __restrict__ out) {
  double v[1] = {0.0};
  for (int k = threadIdx.x; k < 12 * SBLK; k += 256) v[0] += PL[k];
  block_reduce_to0<1>(v);
  if (threadIdx.x == 0) out[0] = (float)(-0.5 * v[0] / (double)MLL);
}

// ---------------- launch ----------------
extern "C" void kernel_launch(void* const* d_in, const int* in_sizes, int n_in,
                              void* d_out, int out_size, void* d_ws, size_t ws_size,
                              hipStream_t stream) {
  const float* x1  = (const float*)d_in[0];
  const float* x2  = (const float*)d_in[1];
  const float* W1  = (const float*)d_in[2];
  const float* b1  = (const float*)d_in[3];
  const float* g1  = (const float*)d_in[4];
  const float* be1 = (const float*)d_in[5];
  const float* W2  = (const float*)d_in[6];
  const float* b2  = (const float*)d_in[7];
  const float* g2  = (const float*)d_in[8];
  const float* be2 = (const float*)d_in[9];
  const float* W3  = (const float*)d_in[10];
  const float* b3  = (const float*)d_in[11];
  const float* g3  = (const float*)d_in[12];
  const float* be3 = (const float*)d_in[13];
  const float* W4  = (const float*)d_in[14];
  const float* b4  = (const float*)d_in[15];
  const float* g4  = (const float*)d_in[16];
  const float* be4 = (const float*)d_in[17];
  const float* W5  = (const float*)d_in[18];
  const float* b5  = (const float*)d_in[19];

  const bool big = ws_size >= NEED_BYTES;
  ushort_t* xh1 = nullptr;
  ushort_t* xh2 = nullptr;
  double* dbase;
  if (big) {
    xh1 = (ushort_t*)d_ws;
    xh2 = xh1 + NTOT;
    dbase = (double*)(xh2 + NTOT);
  } else {
    dbase = (double*)d_ws;
  }
  double* P0 = dbase;
  double* P1 = P0 + P_CNT;
  double* P2 = P1 + P_CNT;
  double* PL = P2 + P_CNT;
  float* derived = (float*)(PL + 12 * SBLK);

  const dim3 blk(256);
  const dim3 gA(16, 192);
  const dim3 gD(16, 96);

  if (big) {
    passA1_kernel<true><<<gA, blk, 0, stream>>>(x1, x2, xh1, xh2, P0);
    stats_fold_kernel<<<24, blk, 0, stream>>>(P0, W1, b1, g1, be1, derived, 0);
    passA2_kernel<true><<<gA, blk, 0, stream>>>(x1, x2, xh1, xh2, derived, P1);
    stats_fold_kernel<<<24, blk, 0, stream>>>(P1, W2, b2, g2, be2, derived, 12);
    passC2_kernel<true><<<gA, blk, 0, stream>>>(x1, x2, xh1, xh2, derived, P2);
    statsC2_kernel<<<24, blk, 0, stream>>>(P2, W3, b3, g3, be3, W4, b4, g4, be4,
                                           derived);
    passD2_kernel<true><<<gD, blk, 0, stream>>>(x1, x2, xh1, xh2, W5, b5,
                                                derived, PL);
  } else {
    passA1_kernel<false><<<gA, blk, 0, stream>>>(x1, x2, nullptr, nullptr, P0);
    stats_fold_kernel<<<24, blk, 0, stream>>>(P0, W1, b1, g1, be1, derived, 0);
    passA2_kernel<false><<<gA, blk, 0, stream>>>(x1, x2, nullptr, nullptr,
                                                 derived, P1);
    stats_fold_kernel<<<24, blk, 0, stream>>>(P1, W2, b2, g2, be2, derived, 12);
    passC2_kernel<false><<<gA, blk, 0, stream>>>(x1, x2, nullptr, nullptr,
                                                 derived, P2);
    statsC2_kernel<<<24, blk, 0, stream>>>(P2, W3, b3, g3, be3, W4, b4, g4, be4,
                                           derived);
    passD2_kernel<false><<<gD, blk, 0, stream>>>(x1, x2, nullptr, nullptr, W5, b5,
                                                 derived, PL);
  }
  finalize_kernel<<<1, blk, 0, stream>>>(PL, (float*)d_out);
}